// Round 6
// baseline (70.086 us; speedup 1.0000x reference)
//
#include <hip/hip_runtime.h>
#include <hip/hip_bf16.h>
#include <stdint.h>

typedef __attribute__((ext_vector_type(8))) short short8;
typedef __attribute__((ext_vector_type(4))) float f32x4;

#define B_   16
#define C_   64
#define H_   112
#define W_   112
#define O_   128
#define HP   114
#define HWP  (HP*HP)          // 12996 padded plane positions
#define HW   (H_*W_)          // 12544
#define XPAD_BYTES ((size_t)B_*HWP*C_*2)   // 26,615,808
#define NROWS 384             // staged A-union rows (need <=362)

__device__ __forceinline__ unsigned short f2bf(float f) {
    union { float f; uint32_t u; } v; v.f = f;
    uint32_t u = v.u;
    u += 0x7fffu + ((u >> 16) & 1u);   // round-to-nearest-even
    return (unsigned short)(u >> 16);
}

// ---------------- Pass 0 (fused): pad-transpose + weight re-layout ----------------
// Blocks [0,1792): x NCHW f32 -> padded NHWC bf16, float4 NT reads.
// Blocks [1792,2080): weight (c,kh,kw,o) f32 -> fragment-ordered bf16.
__global__ void prep(const float* __restrict__ x, const float* __restrict__ wt,
                     unsigned short* __restrict__ xpad,
                     unsigned short* __restrict__ wbuf)
{
    const int t = threadIdx.x;
    if (blockIdx.x >= B_ * H_) {
        // ---- weight re-layout: [s][ks][wc][nf][lane][j], 1KB-coalesced B-fragments
        int f = (blockIdx.x - B_ * H_) * 256 + t;  // [0, 73728)
        int j    = f & 7;
        int lane = (f >> 3) & 63;
        int nf   = (f >> 9) & 3;
        int wc   = (f >> 11) & 1;
        int ks   = (f >> 12) & 1;
        int s    = f >> 13;
        int o = wc * 64 + nf * 16 + (lane & 15);
        int c = (ks * 4 + (lane >> 4)) * 8 + j;
        int kh = s / 3, kw = s % 3;
        wbuf[f] = f2bf(wt[(((size_t)c * 3 + kh) * 3 + kw) * O_ + o]);
        return;
    }

    __shared__ float tile[64][114];   // stride 114: 8B-aligned float2 writes
    const int bh = blockIdx.x;
    const int b = bh / H_, h = bh % H_;

    const float* xr = x + ((size_t)b * C_ * HW) + (size_t)h * W_;  // x[b][0][h][0]
    #pragma unroll
    for (int i = 0; i < 7; ++i) {                  // 64c * 28w4 = 1792 = 7*256
        int flat = i * 256 + t;
        int c = flat / 28, w4 = flat % 28;
        f32x4 v = __builtin_nontemporal_load(
            (const f32x4*)(xr + (size_t)c * HW + (size_t)w4 * 4));
        *(float2*)&tile[c][w4 * 4]     = make_float2(v.x, v.y);
        *(float2*)&tile[c][w4 * 4 + 2] = make_float2(v.z, v.w);
    }

    // Border zeroing (disjoint from interior writes):
    if (t < 64) {
        size_t base = ((size_t)(b * HP + h + 1) * HP) * 64;
        xpad[base + t] = 0;                        // (h+1, 0, ch t)
        xpad[base + (size_t)113 * 64 + t] = 0;     // (h+1, 113, ch t)
    }
    if (h == 0 || h == 111) {                      // full top/bottom halo rows
        const int row = (h == 0) ? 0 : 113;
        size_t base = ((size_t)(b * HP + row) * HP) * 64;
        ushort4 z4; z4.x = z4.y = z4.z = z4.w = 0;
        for (int k = t; k < (HP * 64) / 4; k += 256)
            *(ushort4*)(xpad + base + (size_t)k * 4) = z4;
    }
    __syncthreads();

    unsigned short* dst = xpad + ((size_t)(b * HP + h + 1) * HP + 1) * C_;  // (b,h+1,1,0)
    #pragma unroll
    for (int j = 0; j < 7; ++j) {                  // 112w * 16 c4 = 1792 = 7*256
        int flat = j * 256 + t;
        int w = flat >> 4, c = (flat & 15) * 4;
        ushort4 v;
        v.x = f2bf(tile[c + 0][w]);
        v.y = f2bf(tile[c + 1][w]);
        v.z = f2bf(tile[c + 2][w]);
        v.w = f2bf(tile[c + 3][w]);
        *(ushort4*)(dst + (size_t)w * C_ + c) = v;
    }
}

// ---------------- Pass 1: implicit-GEMM conv, union-staged A, barrier-free K-loop ---
// 3 blocks/CU; stage 362-row union once, one barrier, 288 MFMA/wave, NT epilogue.
__global__ __launch_bounds__(256, 3) void conv_gemm(
    const char* __restrict__ xpad,
    const char* __restrict__ wbuf,
    float* __restrict__ out)
{
    __shared__ char ldsA[NROWS * 128];   // 49152 B

    const int t = threadIdx.x;
    const int lane = t & 63, wid = t >> 6;
    const int wr = wid >> 1, wc = wid & 1;
    const int bid0 = blockIdx.x;
    const int bid = (bid0 & 7) * 196 + (bid0 >> 3);  // XCD swizzle, 1568 = 8*196 exact
    const int b = bid / 98;                 // 98 M-tiles per batch, exact
    const int ml0 = (bid % 98) * 128;
    const int oh0 = ml0 / W_;
    const int pbase = ml0 + 2 * oh0;        // first padded-plane row of the union

    // Stage A-union: 384 rows x 8 chunks = 3072 16B loads = 12 issues/thread.
    // Linear LDS dest + inverse-swizzled global source (rule #21 pattern).
    const char* plane = xpad + (size_t)b * ((size_t)HWP * 128);
    #pragma unroll
    for (int i = 0; i < 12; ++i) {
        const int gbase = i * 256 + wid * 64;       // wave-uniform
        const int g = gbase + lane;
        const int r = g >> 3, ck = g & 7;
        __builtin_amdgcn_global_load_lds(
            (const __attribute__((address_space(1))) void*)
                (plane + (size_t)(pbase + r) * 128 + ((ck ^ (r & 7)) << 4)),
            (__attribute__((address_space(3))) void*)(ldsA + gbase * 16),
            16, 0, 0);
    }
    __syncthreads();   // single barrier: all MFMA data now in LDS

    // Per-fragment LDS base rows (per-lane): row = ml + 2*oh - pbase
    int rowb[4];
    #pragma unroll
    for (int mf = 0; mf < 4; ++mf) {
        int ml = ml0 + wr * 64 + mf * 16 + (lane & 15);
        int oh = ml / W_;
        rowb[mf] = ml + 2 * oh - pbase;
    }
    const int kq = lane >> 4;   // k-quarter 0..3

    f32x4 acc[4][4] = {};

    #pragma unroll
    for (int s = 0; s < 9; ++s) {
        const int kh = s / 3, kw = s % 3;
        const int soff = kh * HP + kw;
        const char* wb = (const char*)wbuf + s * 16384 + wc * 4096 + lane * 16;

        #pragma unroll
        for (int ks = 0; ks < 2; ++ks) {
            // B fragments: 4 coalesced 1KB loads per wave from L2-resident wbuf
            short8 bv[4];
            #pragma unroll
            for (int nf = 0; nf < 4; ++nf)
                bv[nf] = *(const short8*)(wb + ks * 8192 + nf * 1024);

            short8 av[4];
            #pragma unroll
            for (int mf = 0; mf < 4; ++mf) {
                const int lrow = rowb[mf] + soff;
                const int ck = (ks * 4 + kq) ^ (lrow & 7);
                av[mf] = *(const short8*)(ldsA + lrow * 128 + (ck << 4));
            }
            __builtin_amdgcn_s_setprio(1);
            #pragma unroll
            for (int mf = 0; mf < 4; ++mf)
                #pragma unroll
                for (int nf = 0; nf < 4; ++nf)
                    acc[mf][nf] = __builtin_amdgcn_mfma_f32_16x16x32_bf16(
                        av[mf], bv[nf], acc[mf][nf], 0, 0, 0);
            __builtin_amdgcn_s_setprio(0);
        }
    }

    // Epilogue: C/D layout col=lane&15 (o), row=(lane>>4)*4+reg (m).
    // NON-TEMPORAL stores: out is written once, never read -> bypass L2 so
    // xpad union lines survive for neighboring same-XCD blocks.
    const int oc = wc * 64 + (lane & 15);
    const int mrow = ml0 + wr * 64 + ((lane >> 4) << 2);
    #pragma unroll
    for (int mf = 0; mf < 4; ++mf) {
        #pragma unroll
        for (int nf = 0; nf < 4; ++nf) {
            float* dst = out + ((size_t)(b * O_ + oc + nf * 16) * HW) + mrow + mf * 16;
            __builtin_nontemporal_store(acc[mf][nf], (f32x4*)dst);
        }
    }
}

extern "C" void kernel_launch(void* const* d_in, const int* in_sizes, int n_in,
                              void* d_out, int out_size, void* d_ws, size_t ws_size,
                              hipStream_t stream) {
    const float* x  = (const float*)d_in[0];
    const float* wt = (const float*)d_in[1];
    float* out = (float*)d_out;
    char* xpad = (char*)d_ws;
    char* wbuf = (char*)d_ws + XPAD_BYTES;

    hipLaunchKernelGGL(prep, dim3(B_ * H_ + 288), dim3(256), 0, stream,
                       x, wt, (unsigned short*)xpad, (unsigned short*)wbuf);
    hipLaunchKernelGGL(conv_gemm, dim3(1568), dim3(256), 0, stream,
                       xpad, wbuf, out);
}

// Round 7
// 64.905 us; speedup vs baseline: 1.0798x; 1.0798x over previous
//
#include <hip/hip_runtime.h>
#include <hip/hip_bf16.h>
#include <stdint.h>

typedef __attribute__((ext_vector_type(8))) short short8;
typedef __attribute__((ext_vector_type(4))) float f32x4;

#define B_   16
#define C_   64
#define H_   112
#define W_   112
#define O_   128
#define HP   114
#define HWP  (HP*HP)          // 12996 padded plane positions
#define HW   (H_*W_)          // 12544
#define XPAD_BYTES ((size_t)B_*HWP*C_*2)   // 26,615,808
#define NROWS 368             // staged A-union rows (need <=362)

__device__ __forceinline__ unsigned short f2bf(float f) {
    union { float f; uint32_t u; } v; v.f = f;
    uint32_t u = v.u;
    u += 0x7fffu + ((u >> 16) & 1u);   // round-to-nearest-even
    return (unsigned short)(u >> 16);
}

// ---------------- Pass 0 (fused): pad-transpose + weight re-layout ----------------
__global__ void prep(const float* __restrict__ x, const float* __restrict__ wt,
                     unsigned short* __restrict__ xpad,
                     unsigned short* __restrict__ wbuf)
{
    const int t = threadIdx.x;
    if (blockIdx.x >= B_ * H_) {
        // ---- weight re-layout: [s][ks][wc][nf][lane][j], 1KB-coalesced B-fragments
        int f = (blockIdx.x - B_ * H_) * 256 + t;  // [0, 73728)
        int j    = f & 7;
        int lane = (f >> 3) & 63;
        int nf   = (f >> 9) & 3;
        int wc   = (f >> 11) & 1;
        int ks   = (f >> 12) & 1;
        int s    = f >> 13;
        int o = wc * 64 + nf * 16 + (lane & 15);
        int c = (ks * 4 + (lane >> 4)) * 8 + j;
        int kh = s / 3, kw = s % 3;
        wbuf[f] = f2bf(wt[(((size_t)c * 3 + kh) * 3 + kw) * O_ + o]);
        return;
    }

    __shared__ float tile[64][114];   // stride 114: 8B-aligned float2 writes
    const int bh = blockIdx.x;
    const int b = bh / H_, h = bh % H_;

    const float* xr = x + ((size_t)b * C_ * HW) + (size_t)h * W_;  // x[b][0][h][0]
    #pragma unroll
    for (int i = 0; i < 7; ++i) {                  // 64c * 28w4 = 1792 = 7*256
        int flat = i * 256 + t;
        int c = flat / 28, w4 = flat % 28;
        f32x4 v = __builtin_nontemporal_load(
            (const f32x4*)(xr + (size_t)c * HW + (size_t)w4 * 4));
        *(float2*)&tile[c][w4 * 4]     = make_float2(v.x, v.y);
        *(float2*)&tile[c][w4 * 4 + 2] = make_float2(v.z, v.w);
    }

    // Border zeroing (disjoint from interior writes):
    if (t < 64) {
        size_t base = ((size_t)(b * HP + h + 1) * HP) * 64;
        xpad[base + t] = 0;                        // (h+1, 0, ch t)
        xpad[base + (size_t)113 * 64 + t] = 0;     // (h+1, 113, ch t)
    }
    if (h == 0 || h == 111) {                      // full top/bottom halo rows
        const int row = (h == 0) ? 0 : 113;
        size_t base = ((size_t)(b * HP + row) * HP) * 64;
        ushort4 z4; z4.x = z4.y = z4.z = z4.w = 0;
        for (int k = t; k < (HP * 64) / 4; k += 256)
            *(ushort4*)(xpad + base + (size_t)k * 4) = z4;
    }
    __syncthreads();

    unsigned short* dst = xpad + ((size_t)(b * HP + h + 1) * HP + 1) * C_;  // (b,h+1,1,0)
    #pragma unroll
    for (int j = 0; j < 7; ++j) {                  // 112w * 16 c4 = 1792 = 7*256
        int flat = j * 256 + t;
        int w = flat >> 4, c = (flat & 15) * 4;
        ushort4 v;
        v.x = f2bf(tile[c + 0][w]);
        v.y = f2bf(tile[c + 1][w]);
        v.z = f2bf(tile[c + 2][w]);
        v.w = f2bf(tile[c + 3][w]);
        *(ushort4*)(dst + (size_t)w * C_ + c) = v;
    }
}

// ---------------- Pass 1: implicit-GEMM conv ----------------
// A-union staged once (47 KB); B staged per-(kh,kw) slice, double-buffered
// (2x16 KB) -> block B-traffic 147 KB instead of 288 KB (kills the wr-wave
// duplicate L2 stream, the modeled bottleneck). 2 blocks/CU (LDS 78 KB).
__global__ __launch_bounds__(256, 2) void conv_gemm(
    const char* __restrict__ xpad,
    const char* __restrict__ wbuf,
    float* __restrict__ out)
{
    __shared__ char lds[NROWS * 128 + 2 * 16384];   // 47104 + 32768 = 79872 B
    char* ldsA = lds;
    char* ldsB = lds + NROWS * 128;

    const int t = threadIdx.x;
    const int lane = t & 63, wid = t >> 6;
    const int wr = wid >> 1, wc = wid & 1;
    const int bid0 = blockIdx.x;
    const int bid = (bid0 & 7) * 196 + (bid0 >> 3);  // XCD swizzle, 1568 = 8*196 exact
    const int b = bid / 98;                 // 98 M-tiles per batch, exact
    const int ml0 = (bid % 98) * 128;
    const int oh0 = ml0 / W_;
    const int pbase = ml0 + 2 * oh0;        // first padded-plane row of the union

    // Stage A-union: 368 rows x 8 chunks = 2944 16B loads (11.5 issues/thread).
    // Linear LDS dest + inverse-swizzled global source (rule #21 pattern).
    const char* plane = xpad + (size_t)b * ((size_t)HWP * 128);
    #pragma unroll
    for (int i = 0; i < 12; ++i) {
        if (i < 11 || wid < 2) {                    // wave-uniform predicate
            const int gbase = i * 256 + wid * 64;
            const int g = gbase + lane;
            const int r = g >> 3, ck = g & 7;
            __builtin_amdgcn_global_load_lds(
                (const __attribute__((address_space(1))) void*)
                    (plane + (size_t)(pbase + r) * 128 + ((ck ^ (r & 7)) << 4)),
                (__attribute__((address_space(3))) void*)(ldsA + gbase * 16),
                16, 0, 0);
        }
    }
    // Stage B slice 0 into buf 0 (linear copy, wbuf already fragment-ordered)
    #pragma unroll
    for (int i = 0; i < 4; ++i) {
        const int gb = i * 256 + wid * 64;
        __builtin_amdgcn_global_load_lds(
            (const __attribute__((address_space(1))) void*)
                ((const char*)wbuf + (size_t)(gb + lane) * 16),
            (__attribute__((address_space(3))) void*)(ldsB + gb * 16),
            16, 0, 0);
    }
    __syncthreads();

    // Per-fragment LDS base rows (per-lane): row = ml + 2*oh - pbase
    int rowb[4];
    #pragma unroll
    for (int mf = 0; mf < 4; ++mf) {
        int ml = ml0 + wr * 64 + mf * 16 + (lane & 15);
        int oh = ml / W_;
        rowb[mf] = ml + 2 * oh - pbase;
    }
    const int kq = lane >> 4;   // k-quarter 0..3

    f32x4 acc[4][4] = {};

    #pragma unroll
    for (int s = 0; s < 9; ++s) {
        // Prefetch B slice s+1 into the other buffer (covered by MFMA phase)
        if (s < 8) {
            const char* wsl = (const char*)wbuf + (s + 1) * 16384;
            char* dstB = ldsB + ((s + 1) & 1) * 16384;
            #pragma unroll
            for (int i = 0; i < 4; ++i) {
                const int gb = i * 256 + wid * 64;
                __builtin_amdgcn_global_load_lds(
                    (const __attribute__((address_space(1))) void*)
                        (wsl + (size_t)(gb + lane) * 16),
                    (__attribute__((address_space(3))) void*)(dstB + gb * 16),
                    16, 0, 0);
            }
        }

        const int soff = (s / 3) * HP + (s % 3);
        const char* bbase = ldsB + (s & 1) * 16384 + wc * 4096 + lane * 16;

        #pragma unroll
        for (int ks = 0; ks < 2; ++ks) {
            short8 bv[4];
            #pragma unroll
            for (int nf = 0; nf < 4; ++nf)
                bv[nf] = *(const short8*)(bbase + ks * 8192 + nf * 1024);

            short8 av[4];
            #pragma unroll
            for (int mf = 0; mf < 4; ++mf) {
                const int lrow = rowb[mf] + soff;
                const int ck = (ks * 4 + kq) ^ (lrow & 7);
                av[mf] = *(const short8*)(ldsA + lrow * 128 + (ck << 4));
            }
            __builtin_amdgcn_s_setprio(1);
            #pragma unroll
            for (int mf = 0; mf < 4; ++mf)
                #pragma unroll
                for (int nf = 0; nf < 4; ++nf)
                    acc[mf][nf] = __builtin_amdgcn_mfma_f32_16x16x32_bf16(
                        av[mf], bv[nf], acc[mf][nf], 0, 0, 0);
            __builtin_amdgcn_s_setprio(0);
        }
        if (s < 8) __syncthreads();   // next slice staged before it's read
    }

    // Epilogue: C/D layout col=lane&15 (o), row=(lane>>4)*4+reg (m).
    // Normal stores (NT regressed: L2 merges the 16B fragments into 256B runs).
    const int oc = wc * 64 + (lane & 15);
    const int mrow = ml0 + wr * 64 + ((lane >> 4) << 2);
    #pragma unroll
    for (int mf = 0; mf < 4; ++mf) {
        #pragma unroll
        for (int nf = 0; nf < 4; ++nf) {
            float* dst = out + ((size_t)(b * O_ + oc + nf * 16) * HW) + mrow + mf * 16;
            *(f32x4*)dst = acc[mf][nf];
        }
    }
}

extern "C" void kernel_launch(void* const* d_in, const int* in_sizes, int n_in,
                              void* d_out, int out_size, void* d_ws, size_t ws_size,
                              hipStream_t stream) {
    const float* x  = (const float*)d_in[0];
    const float* wt = (const float*)d_in[1];
    float* out = (float*)d_out;
    char* xpad = (char*)d_ws;
    char* wbuf = (char*)d_ws + XPAD_BYTES;

    hipLaunchKernelGGL(prep, dim3(B_ * H_ + 288), dim3(256), 0, stream,
                       x, wt, (unsigned short*)xpad, (unsigned short*)wbuf);
    hipLaunchKernelGGL(conv_gemm, dim3(1568), dim3(256), 0, stream,
                       xpad, wbuf, out);
}